// Round 1
// baseline (687.357 us; speedup 1.0000x reference)
//
#include <hip/hip_runtime.h>
#include <hip/hip_bf16.h>
#include <math.h>

// Problem: discriminative (metric) instance loss.
// B=4, D=64, H=W=512, K=32 clusters. Loss reduces to one-pass sufficient
// statistics per image: cnt[k], sums[k][d], ssq[k] (= sum of ||f_i||^2).
//   segsum(d2)[k] = ssq[k] - cnt[k]*||mu_k||^2  (exact identity)
// so the whole thing is a 260 MB segmented reduction -> memory-bound,
// ~43 us HBM floor at 6.3 TB/s.

#define KSEG 32
#define DF   64
#define STATS_STRIDE 2112   // 32*64 sums + 32 cnt + 32 ssq

// ---------------- Pass 1: per-block partial statistics ----------------
// grid (G, B), 256 threads. Block g of image b handles pixels
// [g*N/G, (g+1)*N/G) across all 64 d's. LDS bins [K][DF+1]: pad 65 words
// => bank = (k*65+d)%32 = (k+d)%32, bijective in k for fixed (uniform) d,
// so only same-label lanes serialize on the ds_add_f32.
__global__ __launch_bounds__(256) void stats_kernel(
    const float* __restrict__ feats, const int* __restrict__ labels,
    float* __restrict__ part, int N, int G) {
  __shared__ float bins[KSEG][DF + 1];
  __shared__ float cnt_s[KSEG];
  __shared__ float ssq_s[KSEG];

  const int g = blockIdx.x, b = blockIdx.y;
  const int tid = threadIdx.x;

  for (int i = tid; i < KSEG * (DF + 1); i += 256) (&bins[0][0])[i] = 0.f;
  if (tid < KSEG) { cnt_s[tid] = 0.f; ssq_s[tid] = 0.f; }
  __syncthreads();

  const int pixPerBlock = N / G;  // 2048 for N=262144, G=128
  const int base = g * pixPerBlock;
  const float* __restrict__ fimg = feats + (size_t)b * DF * N;
  const int* __restrict__ limg = labels + (size_t)b * N;

  for (int i = tid; i < pixPerBlock; i += 256) {
    const int n = base + i;
    const int lab = limg[n] & (KSEG - 1);
    float* row = bins[lab];
    const float* fp = fimg + n;
    float ssq = 0.f;
#pragma unroll
    for (int d = 0; d < DF; ++d) {
      const float f = fp[(size_t)d * N];   // coalesced across lanes
      ssq = fmaf(f, f, ssq);
      atomicAdd(&row[d], f);               // ds_add_f32, non-returning
    }
    atomicAdd(&cnt_s[lab], 1.f);
    atomicAdd(&ssq_s[lab], ssq);
  }
  __syncthreads();

  float* o = part + (size_t)(b * G + g) * STATS_STRIDE;
  for (int i = tid; i < KSEG * DF; i += 256) o[i] = bins[i >> 6][i & 63];
  if (tid < KSEG) {
    o[KSEG * DF + tid] = cnt_s[tid];
    o[KSEG * DF + KSEG + tid] = ssq_s[tid];
  }
}

// ---------------- Pass 2: deterministic tree-reduce of partials ----------------
__global__ __launch_bounds__(256) void reduce_kernel(
    const float* __restrict__ part, float* __restrict__ st, int G, int total) {
  const int idx = blockIdx.x * 256 + threadIdx.x;  // over B*2112
  if (idx >= total) return;
  const int b = idx / STATS_STRIDE, j = idx % STATS_STRIDE;
  const float* p = part + (size_t)b * G * STATS_STRIDE + j;
  float s = 0.f;
  for (int g = 0; g < G; ++g) s += p[(size_t)g * STATS_STRIDE];
  st[idx] = s;
}

// ---------------- Pass 3: finalize (tiny) ----------------
__global__ __launch_bounds__(256) void finalize_kernel(
    const float* __restrict__ st, float* __restrict__ out, int B) {
  __shared__ float mu[KSEG][DF + 1];
  __shared__ float cntS[KSEG], ssqS[KSEG], musqS[KSEG];
  __shared__ float wred[4];
  const int tid = threadIdx.x;
  float total = 0.f;  // only thread 0's copy matters

  for (int b = 0; b < B; ++b) {
    const float* base = st + (size_t)b * STATS_STRIDE;
    if (tid < KSEG) {
      cntS[tid] = base[KSEG * DF + tid];
      ssqS[tid] = base[KSEG * DF + KSEG + tid];
    }
    __syncthreads();
    for (int idx = tid; idx < KSEG * DF; idx += 256) {
      const int k = idx >> 6, d = idx & 63;
      mu[k][d] = base[idx] / fmaxf(cntS[k], 1.f);
    }
    __syncthreads();
    if (tid < KSEG) {
      float m2 = 0.f;
      for (int d = 0; d < DF; ++d) m2 = fmaf(mu[tid][d], mu[tid][d], m2);
      musqS[tid] = m2;
    }
    __syncthreads();

    // pairwise hinge over i<j, both present
    float hacc = 0.f;
    for (int p = tid; p < KSEG * KSEG; p += 256) {
      const int i = p >> 5, j = p & 31;
      if (i < j && cntS[i] > 0.f && cntS[j] > 0.f) {
        float dsq = 0.f;
        for (int d = 0; d < DF; ++d) {
          const float df = mu[i][d] - mu[j][d];
          dsq = fmaf(df, df, dsq);
        }
        const float h = 2.f * 1.5f - sqrtf(dsq);  // 2*DD - dist
        if (h > 0.f) hacc += h * h;
      }
    }
    for (int off = 32; off > 0; off >>= 1) hacc += __shfl_down(hacc, off, 64);
    if ((tid & 63) == 0) wred[tid >> 6] = hacc;
    __syncthreads();

    if (tid == 0) {
      const float dsum = wred[0] + wred[1] + wred[2] + wred[3];
      float var = 0.f, reg = 0.f, ncl = 0.f;
      for (int k = 0; k < KSEG; ++k) {
        const float c = cntS[k];
        if (c > 0.f) {
          ncl += 1.f;
          var += ssqS[k] / c - musqS[k];   // (ssq - c*||mu||^2)/c
          reg += sqrtf(musqS[k]);
        }
      }
      const float dist_loss = dsum / fmaxf(ncl - 1.f, 1.f);
      total += (var + dist_loss + 0.001f * reg) / ncl;
    }
    __syncthreads();  // protect cntS/mu before next image overwrites
  }
  if (tid == 0) out[0] = total / (float)(B + 1);
}

extern "C" void kernel_launch(void* const* d_in, const int* in_sizes, int n_in,
                              void* d_out, int out_size, void* d_ws, size_t ws_size,
                              hipStream_t stream) {
  const float* feats = (const float*)d_in[0];
  const int* labels = (const int*)d_in[1];
  float* out = (float*)d_out;

  const int B = 4;                       // per reference setup_inputs
  const int BHW = in_sizes[1];           // B*H*W
  const int N = BHW / B;                 // pixels per image (262144)
  const int G = 128;                     // partial blocks per image (2 blocks/CU)

  float* part = (float*)d_ws;                                // B*G*2112 floats
  float* st = part + (size_t)B * G * STATS_STRIDE;           // B*2112 floats

  stats_kernel<<<dim3(G, B), 256, 0, stream>>>(feats, labels, part, N, G);
  const int total = B * STATS_STRIDE;
  reduce_kernel<<<(total + 255) / 256, 256, 0, stream>>>(part, st, G, total);
  finalize_kernel<<<1, 256, 0, stream>>>(st, out, B);
}

// Round 2
// 662.771 us; speedup vs baseline: 1.0371x; 1.0371x over previous
//
#include <hip/hip_runtime.h>
#include <hip/hip_bf16.h>
#include <math.h>

// Metric/discriminative instance loss. B=4, D=64, H=W=512, K=32.
// One-pass sufficient statistics: cnt[k], sums[k][d], ssq[k];
//   segsum(||f - mu||^2)[k] = ssq[k] - cnt[k]*||mu_k||^2  (exact).
// 260 MB single sweep -> memory-bound, ~43 us HBM floor.
//
// R1 lesson: scalar dword loads + 8 waves/CU => latency-bound at 389 GB/s.
// R2: float4 loads (16B/lane) + 16 waves/CU.

#define KSEG 32
#define DF   64
#define STATS_STRIDE 2112   // 32*64 sums + 32 cnt + 32 ssq
#define GPI  256            // blocks per image (1024 pixels each)

// ---------------- Pass 1: per-block partial statistics ----------------
// Thread owns 4 consecutive pixels; loops d=0..63 with float4 loads.
// LDS bins [K][DF+1]: pad 65 => bank=(k+d)%32, bijective in k for uniform d,
// so only same-label lanes serialize on ds_add_f32.
__global__ __launch_bounds__(256) void stats_kernel(
    const float* __restrict__ feats, const int* __restrict__ labels,
    float* __restrict__ part, int N) {
  __shared__ float bins[KSEG][DF + 1];
  __shared__ float cnt_s[KSEG];
  __shared__ float ssq_s[KSEG];

  const int g = blockIdx.x, b = blockIdx.y;
  const int tid = threadIdx.x;

  for (int i = tid; i < KSEG * (DF + 1); i += 256) (&bins[0][0])[i] = 0.f;
  if (tid < KSEG) { cnt_s[tid] = 0.f; ssq_s[tid] = 0.f; }
  __syncthreads();

  const float* __restrict__ fimg = feats + (size_t)b * DF * N;
  const int* __restrict__ limg = labels + (size_t)b * N;

  const int pixBase = g * (N / GPI) + 4 * tid;  // N/GPI = 1024 = 4*256 exactly

  const int4 lab4 = *(const int4*)(limg + pixBase);
  const int l0 = lab4.x & (KSEG - 1), l1 = lab4.y & (KSEG - 1);
  const int l2 = lab4.z & (KSEG - 1), l3 = lab4.w & (KSEG - 1);
  float* r0 = bins[l0]; float* r1 = bins[l1];
  float* r2 = bins[l2]; float* r3 = bins[l3];

  float s0 = 0.f, s1 = 0.f, s2 = 0.f, s3 = 0.f;
  const float* fp = fimg + pixBase;
#pragma unroll 8
  for (int d = 0; d < DF; ++d) {
    const float4 f = *(const float4*)(fp + (size_t)d * N);  // 16B/lane coalesced
    s0 = fmaf(f.x, f.x, s0);
    s1 = fmaf(f.y, f.y, s1);
    s2 = fmaf(f.z, f.z, s2);
    s3 = fmaf(f.w, f.w, s3);
    atomicAdd(&r0[d], f.x);
    atomicAdd(&r1[d], f.y);
    atomicAdd(&r2[d], f.z);
    atomicAdd(&r3[d], f.w);
  }
  atomicAdd(&cnt_s[l0], 1.f); atomicAdd(&cnt_s[l1], 1.f);
  atomicAdd(&cnt_s[l2], 1.f); atomicAdd(&cnt_s[l3], 1.f);
  atomicAdd(&ssq_s[l0], s0);  atomicAdd(&ssq_s[l1], s1);
  atomicAdd(&ssq_s[l2], s2);  atomicAdd(&ssq_s[l3], s3);
  __syncthreads();

  float* o = part + (size_t)(b * GPI + g) * STATS_STRIDE;
  for (int i = tid; i < KSEG * DF; i += 256) o[i] = bins[i >> 6][i & 63];
  if (tid < KSEG) {
    o[KSEG * DF + tid] = cnt_s[tid];
    o[KSEG * DF + KSEG + tid] = ssq_s[tid];
  }
}

// ---------------- Pass 2: deterministic tree-reduce of partials ----------------
__global__ __launch_bounds__(256) void reduce_kernel(
    const float* __restrict__ part, float* __restrict__ st, int total) {
  const int idx = blockIdx.x * 256 + threadIdx.x;  // over B*2112
  if (idx >= total) return;
  const int b = idx / STATS_STRIDE, j = idx % STATS_STRIDE;
  const float* p = part + (size_t)b * GPI * STATS_STRIDE + j;
  float s = 0.f;
  for (int g = 0; g < GPI; ++g) s += p[(size_t)g * STATS_STRIDE];
  st[idx] = s;
}

// ---------------- Pass 3: finalize (tiny) ----------------
__global__ __launch_bounds__(256) void finalize_kernel(
    const float* __restrict__ st, float* __restrict__ out, int B) {
  __shared__ float mu[KSEG][DF + 1];
  __shared__ float cntS[KSEG], ssqS[KSEG], musqS[KSEG];
  __shared__ float wred[4];
  const int tid = threadIdx.x;
  float total = 0.f;  // only thread 0's copy matters

  for (int b = 0; b < B; ++b) {
    const float* base = st + (size_t)b * STATS_STRIDE;
    if (tid < KSEG) {
      cntS[tid] = base[KSEG * DF + tid];
      ssqS[tid] = base[KSEG * DF + KSEG + tid];
    }
    __syncthreads();
    for (int idx = tid; idx < KSEG * DF; idx += 256) {
      const int k = idx >> 6, d = idx & 63;
      mu[k][d] = base[idx] / fmaxf(cntS[k], 1.f);
    }
    __syncthreads();
    if (tid < KSEG) {
      float m2 = 0.f;
      for (int d = 0; d < DF; ++d) m2 = fmaf(mu[tid][d], mu[tid][d], m2);
      musqS[tid] = m2;
    }
    __syncthreads();

    // pairwise hinge over i<j, both present
    float hacc = 0.f;
    for (int p = tid; p < KSEG * KSEG; p += 256) {
      const int i = p >> 5, j = p & 31;
      if (i < j && cntS[i] > 0.f && cntS[j] > 0.f) {
        float dsq = 0.f;
        for (int d = 0; d < DF; ++d) {
          const float df = mu[i][d] - mu[j][d];
          dsq = fmaf(df, df, dsq);
        }
        const float h = 2.f * 1.5f - sqrtf(dsq);  // 2*DD - dist
        if (h > 0.f) hacc += h * h;
      }
    }
    for (int off = 32; off > 0; off >>= 1) hacc += __shfl_down(hacc, off, 64);
    if ((tid & 63) == 0) wred[tid >> 6] = hacc;
    __syncthreads();

    if (tid == 0) {
      const float dsum = wred[0] + wred[1] + wred[2] + wred[3];
      float var = 0.f, reg = 0.f, ncl = 0.f;
      for (int k = 0; k < KSEG; ++k) {
        const float c = cntS[k];
        if (c > 0.f) {
          ncl += 1.f;
          var += ssqS[k] / c - musqS[k];
          reg += sqrtf(musqS[k]);
        }
      }
      const float dist_loss = dsum / fmaxf(ncl - 1.f, 1.f);
      total += (var + dist_loss + 0.001f * reg) / ncl;
    }
    __syncthreads();
  }
  if (tid == 0) out[0] = total / (float)(B + 1);
}

extern "C" void kernel_launch(void* const* d_in, const int* in_sizes, int n_in,
                              void* d_out, int out_size, void* d_ws, size_t ws_size,
                              hipStream_t stream) {
  const float* feats = (const float*)d_in[0];
  const int* labels = (const int*)d_in[1];
  float* out = (float*)d_out;

  const int B = 4;
  const int BHW = in_sizes[1];
  const int N = BHW / B;  // 262144

  float* part = (float*)d_ws;                                 // B*GPI*2112 floats
  float* st = part + (size_t)B * GPI * STATS_STRIDE;          // B*2112 floats

  stats_kernel<<<dim3(GPI, B), 256, 0, stream>>>(feats, labels, part, N);
  const int total = B * STATS_STRIDE;
  reduce_kernel<<<(total + 255) / 256, 256, 0, stream>>>(part, st, total);
  finalize_kernel<<<1, 256, 0, stream>>>(st, out, B);
}

// Round 3
// 420.273 us; speedup vs baseline: 1.6355x; 1.5770x over previous
//
#include <hip/hip_runtime.h>
#include <hip/hip_bf16.h>
#include <math.h>

// Metric/discriminative instance loss. B=4, D=64, H=W=512, K=32.
// Sufficient stats as one-hot GEMM via MFMA (no LDS atomics — R2 showed
// ds_add_f32 costs ~206 cyc/wave-instr with same-address collisions):
//   sums[k][d] = onehot[k][pix] @ f[pix][d]
//   ssq[k]     = onehot @ f^2  (then sum over d)
//   cnt[k]     = onehot @ 1
// var identity: segsum(||f-mu||^2)[k] = ssq[k] - cnt[k]*||mu_k||^2.
// Memory floor ~43 us (260 MB @ 6.3 TB/s).

#define KSEG 32
#define DF   64
#define STATS_STRIDE 2112   // 32*64 sums + 32 cnt + 32 ssq
#define GPB  512            // blocks per image; 512 pixels/block = 16 chunks

typedef _Float16 half8 __attribute__((ext_vector_type(8)));
typedef float f32x4 __attribute__((ext_vector_type(4)));

// ---------------- Pass 1: MFMA one-hot stats, atomic-accumulated to st ----------------
// Block: 256 thr = 4 waves. Wave w owns d in [16w, 16w+16). Lane l: m=l&15
// (cluster row for A / d-col for B), q=l>>4 (8-pixel group within 32-chunk).
__global__ __launch_bounds__(256) void stats_kernel(
    const float* __restrict__ feats, const int* __restrict__ labels,
    float* __restrict__ st, int N) {
  const int b = blockIdx.y, g = blockIdx.x;
  const int tid = threadIdx.x;
  const int w = tid >> 6, lane = tid & 63;
  const int m = lane & 15, q = lane >> 4;

  const float* __restrict__ fimg = feats + (size_t)b * DF * N;
  const int* __restrict__ limg = labels + (size_t)b * N;
  const int pix0 = g * (N / GPB);          // 512 pixels per block
  const int d = 16 * w + m;
  const float* __restrict__ frow = fimg + (size_t)d * N;

  f32x4 c_sum0 = {0.f, 0.f, 0.f, 0.f}, c_sum1 = {0.f, 0.f, 0.f, 0.f};
  f32x4 c_sq0 = {0.f, 0.f, 0.f, 0.f}, c_sq1 = {0.f, 0.f, 0.f, 0.f};
  f32x4 c_cn0 = {0.f, 0.f, 0.f, 0.f}, c_cn1 = {0.f, 0.f, 0.f, 0.f};
  const _Float16 h1 = (_Float16)1.0f, h0 = (_Float16)0.0f;
  half8 ones = {h1, h1, h1, h1, h1, h1, h1, h1};

#pragma unroll 4
  for (int c = 0; c < 16; ++c) {           // 16 chunks of 32 pixels
    const int pb = pix0 + c * 32 + q * 8;  // lane's 8 consecutive pixels
    const float4 fA = *(const float4*)(frow + pb);
    const float4 fB = *(const float4*)(frow + pb + 4);
    const int4 lA = *(const int4*)(limg + pb);
    const int4 lB = *(const int4*)(limg + pb + 4);

    float fv[8] = {fA.x, fA.y, fA.z, fA.w, fB.x, fB.y, fB.z, fB.w};
    int lv[8] = {lA.x, lA.y, lA.z, lA.w, lB.x, lB.y, lB.z, lB.w};

    half8 bf, bsq, a0, a1;
#pragma unroll
    for (int j = 0; j < 8; ++j) {
      const _Float16 h = (_Float16)fv[j];  // v_cvt_f16_f32, RNE (unbiased)
      bf[j] = h;
      bsq[j] = h * h;
      a0[j] = (lv[j] == m) ? h1 : h0;
      a1[j] = (lv[j] == m + 16) ? h1 : h0;
    }
    c_sum0 = __builtin_amdgcn_mfma_f32_16x16x32_f16(a0, bf, c_sum0, 0, 0, 0);
    c_sum1 = __builtin_amdgcn_mfma_f32_16x16x32_f16(a1, bf, c_sum1, 0, 0, 0);
    c_sq0 = __builtin_amdgcn_mfma_f32_16x16x32_f16(a0, bsq, c_sq0, 0, 0, 0);
    c_sq1 = __builtin_amdgcn_mfma_f32_16x16x32_f16(a1, bsq, c_sq1, 0, 0, 0);
    c_cn0 = __builtin_amdgcn_mfma_f32_16x16x32_f16(a0, ones, c_cn0, 0, 0, 0);
    c_cn1 = __builtin_amdgcn_mfma_f32_16x16x32_f16(a1, ones, c_cn1, 0, 0, 0);
  }

  // Block-level assembly in LDS (each cell written exactly once), then
  // device-scope atomicAdd into the per-image stat vector st[b][2112].
  __shared__ float lsum[KSEG][DF + 1];
  __shared__ float lssq[KSEG][DF + 1];
  __shared__ float lcnt[KSEG];
#pragma unroll
  for (int r = 0; r < 4; ++r) {
    const int k0 = q * 4 + r;              // C/D: row=(lane>>4)*4+reg
    lsum[k0][16 * w + m] = c_sum0[r];
    lsum[k0 + 16][16 * w + m] = c_sum1[r];
    lssq[k0][16 * w + m] = c_sq0[r];
    lssq[k0 + 16][16 * w + m] = c_sq1[r];
  }
  if (w == 0 && m == 0) {                  // cnt: all d-cols identical; take col 0
#pragma unroll
    for (int r = 0; r < 4; ++r) {
      lcnt[q * 4 + r] = c_cn0[r];
      lcnt[16 + q * 4 + r] = c_cn1[r];
    }
  }
  __syncthreads();

  float* so = st + (size_t)b * STATS_STRIDE;
  for (int i = tid; i < KSEG * DF; i += 256)
    atomicAdd(&so[i], lsum[i >> 6][i & 63]);
  if (tid < KSEG) {
    float s = 0.f;
    for (int dd = 0; dd < DF; ++dd) s += lssq[tid][dd];  // conflict-free: (tid+dd)%32
    atomicAdd(&so[KSEG * DF + tid], lcnt[tid]);
    atomicAdd(&so[KSEG * DF + KSEG + tid], s);
  }
}

// ---------------- Pass 2: finalize (tiny) ----------------
__global__ __launch_bounds__(256) void finalize_kernel(
    const float* __restrict__ st, float* __restrict__ out, int B) {
  __shared__ float mu[KSEG][DF + 1];
  __shared__ float cntS[KSEG], ssqS[KSEG], musqS[KSEG];
  __shared__ float wred[4];
  const int tid = threadIdx.x;
  float total = 0.f;

  for (int b = 0; b < B; ++b) {
    const float* base = st + (size_t)b * STATS_STRIDE;
    if (tid < KSEG) {
      cntS[tid] = base[KSEG * DF + tid];
      ssqS[tid] = base[KSEG * DF + KSEG + tid];
    }
    __syncthreads();
    for (int idx = tid; idx < KSEG * DF; idx += 256) {
      const int k = idx >> 6, dd = idx & 63;
      mu[k][dd] = base[idx] / fmaxf(cntS[k], 1.f);
    }
    __syncthreads();
    if (tid < KSEG) {
      float m2 = 0.f;
      for (int dd = 0; dd < DF; ++dd) m2 = fmaf(mu[tid][dd], mu[tid][dd], m2);
      musqS[tid] = m2;
    }
    __syncthreads();

    float hacc = 0.f;
    for (int p = tid; p < KSEG * KSEG; p += 256) {
      const int i = p >> 5, j = p & 31;
      if (i < j && cntS[i] > 0.f && cntS[j] > 0.f) {
        float dsq = 0.f;
        for (int dd = 0; dd < DF; ++dd) {
          const float df = mu[i][dd] - mu[j][dd];
          dsq = fmaf(df, df, dsq);
        }
        const float h = 2.f * 1.5f - sqrtf(dsq);  // 2*DD - dist
        if (h > 0.f) hacc += h * h;
      }
    }
    for (int off = 32; off > 0; off >>= 1) hacc += __shfl_down(hacc, off, 64);
    if ((tid & 63) == 0) wred[tid >> 6] = hacc;
    __syncthreads();

    if (tid == 0) {
      const float dsum = wred[0] + wred[1] + wred[2] + wred[3];
      float var = 0.f, reg = 0.f, ncl = 0.f;
      for (int k = 0; k < KSEG; ++k) {
        const float c = cntS[k];
        if (c > 0.f) {
          ncl += 1.f;
          var += ssqS[k] / c - musqS[k];
          reg += sqrtf(musqS[k]);
        }
      }
      const float dist_loss = dsum / fmaxf(ncl - 1.f, 1.f);
      total += (var + dist_loss + 0.001f * reg) / ncl;
    }
    __syncthreads();
  }
  if (tid == 0) out[0] = total / (float)(B + 1);
}

extern "C" void kernel_launch(void* const* d_in, const int* in_sizes, int n_in,
                              void* d_out, int out_size, void* d_ws, size_t ws_size,
                              hipStream_t stream) {
  const float* feats = (const float*)d_in[0];
  const int* labels = (const int*)d_in[1];
  float* out = (float*)d_out;

  const int B = 4;
  const int BHW = in_sizes[1];
  const int N = BHW / B;  // 262144

  float* st = (float*)d_ws;  // B*2112 floats, atomically accumulated
  hipMemsetAsync(st, 0, (size_t)B * STATS_STRIDE * sizeof(float), stream);

  stats_kernel<<<dim3(GPB, B), 256, 0, stream>>>(feats, labels, st, N);
  finalize_kernel<<<1, 256, 0, stream>>>(st, out, B);
}